// Round 4
// baseline (7475.147 us; speedup 1.0000x reference)
//
#include <hip/hip_runtime.h>
#include <hip/hip_bf16.h>
#include <stdint.h>

#define HID 1024
#define G4H 4096
#define BATCH 4096
#define TSTEPS 28
#define DIN 28
#define KTOT 1056   // 1024 (h) + 28 (x_t) + 4 zero pad = 33 * 32
#define NKEY 8
#define NTILES 33
#define NBLK 512

typedef __attribute__((ext_vector_type(8))) __bf16 b16x8;
typedef __attribute__((ext_vector_type(4))) __bf16 b16x4;
typedef __attribute__((ext_vector_type(4))) float f32x4;
typedef __attribute__((address_space(1))) unsigned int u32_g;
typedef __attribute__((address_space(3))) unsigned int u32_l;

__device__ __forceinline__ void async16(const __hip_bfloat16* g, __hip_bfloat16* l) {
  __builtin_amdgcn_global_load_lds((u32_g*)g, (u32_l*)l, 16, 0, 0);
}

__device__ __forceinline__ float sigmoidf_(float x) { return 1.f / (1.f + __expf(-x)); }
__device__ __forceinline__ float tanhfast_(float x) { return 2.f / (1.f + __expf(-2.f * x)) - 1.f; }

__device__ __forceinline__ int nprime(int gate, int j) {
  return ((j >> 4) << 6) + (gate << 4) + (j & 15);
}

// device-scope grid barrier (monotonic counter, sense-free)
__device__ __forceinline__ void gridbar(unsigned* cnt, unsigned target) {
  __threadfence();                 // release: h/x writes visible agent-wide
  __syncthreads();
  if (threadIdx.x == 0) {
    __hip_atomic_fetch_add(cnt, 1u, __ATOMIC_RELEASE, __HIP_MEMORY_SCOPE_AGENT);
    unsigned v;
    do {
      __builtin_amdgcn_s_sleep(2);
      v = __hip_atomic_load(cnt, __ATOMIC_ACQUIRE, __HIP_MEMORY_SCOPE_AGENT);
    } while (v < target);
  }
  __syncthreads();
  __threadfence();                 // acquire: invalidate stale cached lines
}

// ---- one-time: Wt[n'][k] bf16, n' gate-interleaved; zero hk0+ck ----
__global__ __launch_bounds__(256) void prep_weights(
    const float* __restrict__ W_hh, const float* __restrict__ W_ih,
    __hip_bfloat16* __restrict__ Wt, float* __restrict__ kstate) {
  __shared__ float tile[64][65];
  const int k0 = blockIdx.x * 64, n0 = blockIdx.y * 64;
  const int tid = threadIdx.x;
  const int fid = (blockIdx.y * gridDim.x + blockIdx.x) * 256 + tid;
  if (fid < 2 * NKEY * HID) kstate[fid] = 0.f;
  for (int i = tid; i < 4096; i += 256) {
    int kk = i >> 6, nn = i & 63;
    int k = k0 + kk;
    float v = 0.f;
    if (k < HID) v = W_hh[k * G4H + n0 + nn];
    else if (k < HID + DIN) v = W_ih[(k - HID) * G4H + n0 + nn];
    tile[kk][nn] = v;
  }
  __syncthreads();
  for (int i = tid; i < 4096; i += 256) {
    int nn = i >> 6, kk = i & 63;
    int k = k0 + kk;
    int n = n0 + nn;
    int np = nprime(n >> 10, n & 1023);
    if (k < KTOT) Wt[(size_t)np * KTOT + k] = __float2bfloat16(tile[kk][nn]);
  }
}

// ---- key pass: one fused step ----
__global__ __launch_bounds__(256) void key_step(
    const __hip_bfloat16* __restrict__ Wt, const float* __restrict__ key_seq,
    const float* __restrict__ bias, const float* __restrict__ hk_in,
    float* __restrict__ hk_out, float* __restrict__ ck, int t) {
  __shared__ float sh[NKEY][KTOT];
  __shared__ float sred[32][8][8];
  const int tid = threadIdx.x;
#pragma unroll
  for (int key = 0; key < NKEY; ++key)
    for (int k = tid; k < HID; k += 256) sh[key][k] = hk_in[key * HID + k];
  for (int i = tid; i < NKEY * 32; i += 256) {
    int key = i >> 5, d = i & 31;
    sh[key][HID + d] = (d < DIN) ? key_seq[key * (TSTEPS * DIN) + t * DIN + d] : 0.f;
  }
  __syncthreads();
  const int rowIdx = tid >> 3;
  const int kpart = tid & 7;
  const int gate = rowIdx >> 3, jj = rowIdx & 7;
  const int j0 = blockIdx.x * 8;
  const int np = nprime(gate, j0 + jj);
  const __hip_bfloat16* wrow = Wt + (size_t)np * KTOT + kpart * 132;
  const int kb = kpart * 132;
  float acc[NKEY];
#pragma unroll
  for (int key = 0; key < NKEY; ++key) acc[key] = 0.f;
  for (int kk = 0; kk < 132; kk += 4) {
    b16x4 wv = *(const b16x4*)(wrow + kk);
    float w0 = (float)wv[0], w1 = (float)wv[1], w2 = (float)wv[2], w3 = (float)wv[3];
#pragma unroll
    for (int key = 0; key < NKEY; ++key) {
      const float* s = &sh[key][kb + kk];
      acc[key] += w0 * s[0] + w1 * s[1] + w2 * s[2] + w3 * s[3];
    }
  }
#pragma unroll
  for (int key = 0; key < NKEY; ++key) sred[rowIdx][kpart][key] = acc[key];
  __syncthreads();
  if (tid < 64) {
    int key = tid >> 3, j2 = tid & 7;
    float g[4];
#pragma unroll
    for (int gg = 0; gg < 4; ++gg) {
      float s = 0.f;
#pragma unroll
      for (int p = 0; p < 8; ++p) s += sred[gg * 8 + j2][p][key];
      g[gg] = s + bias[gg * HID + j0 + j2];
    }
    size_t ci = (size_t)key * HID + j0 + j2;
    float cv = sigmoidf_(g[1]) * ck[ci] + sigmoidf_(g[0]) * tanhfast_(g[2]);
    ck[ci] = cv;
    hk_out[ci] = sigmoidf_(g[3]) * tanhfast_(cv);
  }
}

__global__ __launch_bounds__(256) void key_mean(
    const float* __restrict__ hk, const float* __restrict__ ck,
    float* __restrict__ h0, float* __restrict__ c0) {
  int j = blockIdx.x * 256 + threadIdx.x;
  float sh_ = 0.f, sc_ = 0.f;
#pragma unroll
  for (int k = 0; k < NKEY; ++k) { sh_ += hk[k * HID + j]; sc_ += ck[k * HID + j]; }
  h0[j] = sh_ * (1.f / NKEY);
  c0[j] = sc_ * (1.f / NKEY);
}

// ---- main pass init: A0 = [bf16(h0) | bf16(x0) | 0], zero pads of A1 ----
__global__ __launch_bounds__(256) void main_init(
    const float* __restrict__ h0, const float* __restrict__ x,
    __hip_bfloat16* __restrict__ A0, __hip_bfloat16* __restrict__ A1) {
  int idx = blockIdx.x * 256 + threadIdx.x;  // 4096*1056
  int b = idx / KTOT, col = idx - b * KTOT;
  if (col < HID) {
    A0[idx] = __float2bfloat16(h0[col]);
  } else if (col < HID + DIN) {
    A0[idx] = __float2bfloat16(x[b * (TSTEPS * DIN) + (col - HID)]);
  } else {
    A0[idx] = __float2bfloat16(0.f);
    A1[idx] = __float2bfloat16(0.f);
  }
}

// ---- persistent fused LSTM: 28 steps, c in registers, grid barrier/step ----
// 512 blocks x 256 thr (2 blocks/CU). Tile 256 rows x 128 n' (32 j x 4 gates).
__global__ __launch_bounds__(256, 2) void lstm_persist(
    const __hip_bfloat16* __restrict__ Wt,
    __hip_bfloat16* __restrict__ A0, __hip_bfloat16* __restrict__ A1,
    const float* __restrict__ bias, const float* __restrict__ c0,
    const float* __restrict__ x, float* __restrict__ hfin,
    unsigned* __restrict__ barcnt) {
  __shared__ alignas(16) __hip_bfloat16 sA[2][256 * 32];   // 32 KB
  __shared__ alignas(16) __hip_bfloat16 sB[2][128 * 32];   // 16 KB
  const int tid = threadIdx.x;
  const int lane = tid & 63, wave = tid >> 6;     // 4 waves, 2M x 2N
  const int wr = wave >> 1, wc = wave & 1;
  const int bid = blockIdx.x;
  // XCD chunking: xcd = bid&7 -> (mt-chunk of 8) x (jt-chunk of 8)
  const int q = bid >> 3;
  const int mt = ((bid >> 2) & 1) * 8 + (q >> 3);   // 0..15
  const int jt = (bid & 3) * 8 + (q & 7);           // 0..31
  const int brow = mt * 256;
  const int lrow = lane & 15, kq = lane >> 4;
  const int sx = (lrow >> 1) & 3;

  // staging offsets (element units), k-slot XOR-swizzled at the source
  int aoff[4], boff[2];
#pragma unroll
  for (int r = 0; r < 4; ++r) {
    int g = r * 256 + tid;
    int row = g >> 2, slot = (g & 3) ^ ((g >> 3) & 3);
    aoff[r] = (brow + row) * KTOT + slot * 8;
  }
#pragma unroll
  for (int r = 0; r < 2; ++r) {
    int g = r * 256 + tid;
    int row = g >> 2, slot = (g & 3) ^ ((g >> 3) & 3);
    boff[r] = (jt * 128 + row) * KTOT + slot * 8;
  }
  // fragment ds_read granule indices (16B units)
  int iA[8], iB4[4];
#pragma unroll
  for (int m = 0; m < 8; ++m) iA[m] = (wr * 128 + m * 16 + lrow) * 4 + (kq ^ sx);
#pragma unroll
  for (int g = 0; g < 4; ++g) iB4[g] = (wc * 64 + g * 16 + lrow) * 4 + (kq ^ sx);

  const int j = jt * 32 + wc * 16 + lrow;
  const float b_i = bias[j], b_f = bias[HID + j];
  const float b_g = bias[2 * HID + j], b_o = bias[3 * HID + j];
  float cst[8][4];
  const float cinit = c0[j];
#pragma unroll
  for (int m = 0; m < 8; ++m)
#pragma unroll
    for (int r = 0; r < 4; ++r) cst[m][r] = cinit;

#pragma unroll 1
  for (int s = 0; s < TSTEPS; ++s) {
    const __hip_bfloat16* ain = (s & 1) ? A1 : A0;
    __hip_bfloat16* aout = (s & 1) ? A0 : A1;
    f32x4 acc[8][4] = {};   // [m][gate]

    // stage tile 0
#pragma unroll
    for (int r = 0; r < 4; ++r) async16(ain + aoff[r], &sA[0][(r * 256 + tid) * 8]);
#pragma unroll
    for (int r = 0; r < 2; ++r) async16(Wt + boff[r], &sB[0][(r * 256 + tid) * 8]);
    __syncthreads();

#pragma unroll 1
    for (int t = 0; t < NTILES; ++t) {
      if (t < NTILES - 1) {
        const int ko = (t + 1) * 32;
        const int nb = (t + 1) & 1;
#pragma unroll
        for (int r = 0; r < 4; ++r) async16(ain + aoff[r] + ko, &sA[nb][(r * 256 + tid) * 8]);
#pragma unroll
        for (int r = 0; r < 2; ++r) async16(Wt + boff[r] + ko, &sB[nb][(r * 256 + tid) * 8]);
      }
      const b16x8* cA = (const b16x8*)sA[t & 1];
      const b16x8* cB = (const b16x8*)sB[t & 1];
      b16x8 bf[4];
#pragma unroll
      for (int g = 0; g < 4; ++g) bf[g] = cB[iB4[g]];
      __builtin_amdgcn_s_setprio(1);
#pragma unroll
      for (int m = 0; m < 8; ++m) {
        b16x8 af = cA[iA[m]];
#pragma unroll
        for (int g = 0; g < 4; ++g)
          acc[m][g] = __builtin_amdgcn_mfma_f32_16x16x32_bf16(af, bf[g], acc[m][g], 0, 0, 0);
      }
      __builtin_amdgcn_s_setprio(0);
      __syncthreads();   // drains staged loads + fragment reads
    }

    // ---- LSTM cell epilogue: gates -> c(reg) -> h -> LDS transpose ----
    __hip_bfloat16* sH = &sA[0][0];   // [256][32] bf16
#pragma unroll
    for (int m = 0; m < 8; ++m)
#pragma unroll
      for (int r = 0; r < 4; ++r) {
        float gi = acc[m][0][r] + b_i;
        float gf = acc[m][1][r] + b_f;
        float gg = acc[m][2][r] + b_g;
        float go = acc[m][3][r] + b_o;
        float cv = sigmoidf_(gf) * cst[m][r] + sigmoidf_(gi) * tanhfast_(gg);
        cst[m][r] = cv;
        float h = sigmoidf_(go) * tanhfast_(cv);
        const int lr = wr * 128 + m * 16 + kq * 4 + r;
        sH[lr * 32 + wc * 16 + lrow] = __float2bfloat16(h);
        if (s == TSTEPS - 1) hfin[(size_t)(brow + lr) * HID + j] = h;
      }
    __syncthreads();
    {
      const b16x8* sHv = (const b16x8*)sH;
      __hip_bfloat16* dst = aout + (size_t)(brow + tid) * KTOT + jt * 32;
#pragma unroll
      for (int qq = 0; qq < 4; ++qq)
        *(b16x8*)(dst + qq * 8) = sHv[tid * 4 + qq];
    }
    if (jt == 0 && s + 1 < TSTEPS) {
      const float* xr = x + (size_t)(brow + tid) * (TSTEPS * DIN) + (s + 1) * DIN;
      __hip_bfloat16* ar = aout + (size_t)(brow + tid) * KTOT + HID;
#pragma unroll
      for (int d = 0; d < DIN; ++d) ar[d] = __float2bfloat16(xr[d]);
    }
    if (s + 1 < TSTEPS) gridbar(barcnt, (unsigned)(NBLK * (s + 1)));
  }
}

// ---- out = hfin @ W_cls + b_cls ----
__global__ __launch_bounds__(256) void classifier(
    const float* __restrict__ hfin, const float* __restrict__ W_cls,
    const float* __restrict__ b_cls, float* __restrict__ out) {
  __shared__ float sw[HID * 10];
  __shared__ float sred[10][257];
  const int b = blockIdx.x, tid = threadIdx.x;
  for (int i = tid; i < HID * 10; i += 256) sw[i] = W_cls[i];
  __syncthreads();
  float acc[10];
#pragma unroll
  for (int cls = 0; cls < 10; ++cls) acc[cls] = 0.f;
  for (int j = tid; j < HID; j += 256) {
    float hv = hfin[(size_t)b * HID + j];
#pragma unroll
    for (int cls = 0; cls < 10; ++cls) acc[cls] += hv * sw[j * 10 + cls];
  }
#pragma unroll
  for (int cls = 0; cls < 10; ++cls) sred[cls][tid] = acc[cls];
  __syncthreads();
  for (int off = 128; off > 0; off >>= 1) {
    if (tid < off)
#pragma unroll
      for (int cls = 0; cls < 10; ++cls) sred[cls][tid] += sred[cls][tid + off];
    __syncthreads();
  }
  if (tid < 10) out[b * 10 + tid] = sred[tid][0] + b_cls[tid];
}

extern "C" void kernel_launch(void* const* d_in, const int* in_sizes, int n_in,
                              void* d_out, int out_size, void* d_ws, size_t ws_size,
                              hipStream_t stream) {
  const float* x      = (const float*)d_in[0];
  const float* keyseq = (const float*)d_in[1];
  const float* W_ih   = (const float*)d_in[2];
  const float* W_hh   = (const float*)d_in[3];
  const float* bias   = (const float*)d_in[4];
  const float* W_cls  = (const float*)d_in[5];
  const float* b_cls  = (const float*)d_in[6];
  float* out = (float*)d_out;
  (void)in_sizes; (void)n_in; (void)out_size; (void)ws_size;

  char* p = (char*)d_ws;
  auto alloc = [&](size_t bytes) { char* r = p; p += (bytes + 255) & ~(size_t)255; return r; };
  __hip_bfloat16* Wt = (__hip_bfloat16*)alloc((size_t)G4H * KTOT * 2);
  __hip_bfloat16* A0 = (__hip_bfloat16*)alloc((size_t)BATCH * KTOT * 2);
  __hip_bfloat16* A1 = (__hip_bfloat16*)alloc((size_t)BATCH * KTOT * 2);
  float* hfin = (float*)alloc((size_t)BATCH * HID * 4);
  float* hk0  = (float*)alloc((size_t)NKEY * HID * 4);   // hk0 then ck contiguous
  float* ck   = (float*)alloc((size_t)NKEY * HID * 4);
  float* hk1  = (float*)alloc((size_t)NKEY * HID * 4);
  float* h0   = (float*)alloc((size_t)HID * 4);
  float* c0   = (float*)alloc((size_t)HID * 4);
  unsigned* barcnt = (unsigned*)alloc(256);

  prep_weights<<<dim3(17, 64), 256, 0, stream>>>(W_hh, W_ih, Wt, hk0);

  float* kbuf[2] = {hk0, hk1};
  for (int t = 0; t < TSTEPS; ++t)
    key_step<<<128, 256, 0, stream>>>(Wt, keyseq, bias, kbuf[t & 1], kbuf[(t + 1) & 1], ck, t);
  key_mean<<<4, 256, 0, stream>>>(hk0, ck, h0, c0);

  main_init<<<(BATCH * KTOT) / 256, 256, 0, stream>>>(h0, x, A0, A1);
  hipMemsetAsync(barcnt, 0, 256, stream);

  lstm_persist<<<NBLK, 256, 0, stream>>>(Wt, A0, A1, bias, c0, x, hfin, barcnt);

  classifier<<<BATCH, 256, 0, stream>>>(hfin, W_cls, b_cls, out);
}

// Round 6
// 2629.861 us; speedup vs baseline: 2.8424x; 2.8424x over previous
//
#include <hip/hip_runtime.h>
#include <hip/hip_bf16.h>
#include <stdint.h>

#define HID 1024
#define G4H 4096
#define BATCH 4096
#define TSTEPS 28
#define DIN 28
#define KTOT 1056   // 1024 (h) + 28 (x_t) + 4 zero pad = 33 * 32
#define NKEY 8
#define NTILES 33

typedef __attribute__((ext_vector_type(8))) __bf16 b16x8;
typedef __attribute__((ext_vector_type(4))) __bf16 b16x4;
typedef __attribute__((ext_vector_type(4))) float f32x4;
typedef __attribute__((address_space(1))) unsigned int u32_g;
typedef __attribute__((address_space(3))) unsigned int u32_l;

__device__ __forceinline__ void async16(const __hip_bfloat16* g, __hip_bfloat16* l) {
  __builtin_amdgcn_global_load_lds((u32_g*)g, (u32_l*)l, 16, 0, 0);
}

__device__ __forceinline__ float sigmoidf_(float x) { return 1.f / (1.f + __expf(-x)); }
__device__ __forceinline__ float tanhfast_(float x) { return 2.f / (1.f + __expf(-2.f * x)) - 1.f; }

__device__ __forceinline__ int nprime(int gate, int j) {
  return ((j >> 4) << 6) + (gate << 4) + (j & 15);
}

// ---- one-time: Wt[n'][k] bf16 (n' = gate-interleaved) ; zero hk0+ck ----
__global__ __launch_bounds__(256) void prep_weights(
    const float* __restrict__ W_hh, const float* __restrict__ W_ih,
    __hip_bfloat16* __restrict__ Wt, float* __restrict__ kstate) {
  __shared__ float tile[64][65];
  const int k0 = blockIdx.x * 64, n0 = blockIdx.y * 64;
  const int tid = threadIdx.x;
  const int fid = (blockIdx.y * gridDim.x + blockIdx.x) * 256 + tid;
  if (fid < 2 * NKEY * HID) kstate[fid] = 0.f;
  for (int i = tid; i < 4096; i += 256) {
    int kk = i >> 6, nn = i & 63;
    int k = k0 + kk;
    float v = 0.f;
    if (k < HID) v = W_hh[k * G4H + n0 + nn];
    else if (k < HID + DIN) v = W_ih[(k - HID) * G4H + n0 + nn];
    tile[kk][nn] = v;
  }
  __syncthreads();
  for (int i = tid; i < 4096; i += 256) {
    int nn = i >> 6, kk = i & 63;
    int k = k0 + kk;
    int n = n0 + nn;
    int np = nprime(n >> 10, n & 1023);
    if (k < KTOT) Wt[(size_t)np * KTOT + k] = __float2bfloat16(tile[kk][nn]);
  }
}

// ---- key pass: one fused step (bf16 weights, fp32 math) ----
__global__ __launch_bounds__(256) void key_step(
    const __hip_bfloat16* __restrict__ Wt, const float* __restrict__ key_seq,
    const float* __restrict__ bias, const float* __restrict__ hk_in,
    float* __restrict__ hk_out, float* __restrict__ ck, int t) {
  __shared__ float sh[NKEY][KTOT];
  __shared__ float sred[32][8][8];
  const int tid = threadIdx.x;
#pragma unroll
  for (int key = 0; key < NKEY; ++key)
    for (int k = tid; k < HID; k += 256) sh[key][k] = hk_in[key * HID + k];
  for (int i = tid; i < NKEY * 32; i += 256) {
    int key = i >> 5, d = i & 31;
    sh[key][HID + d] = (d < DIN) ? key_seq[key * (TSTEPS * DIN) + t * DIN + d] : 0.f;
  }
  __syncthreads();
  const int rowIdx = tid >> 3;
  const int kpart = tid & 7;
  const int gate = rowIdx >> 3, jj = rowIdx & 7;
  const int j0 = blockIdx.x * 8;
  const int np = nprime(gate, j0 + jj);
  const __hip_bfloat16* wrow = Wt + (size_t)np * KTOT + kpart * 132;
  const int kb = kpart * 132;
  float acc[NKEY];
#pragma unroll
  for (int key = 0; key < NKEY; ++key) acc[key] = 0.f;
  for (int kk = 0; kk < 132; kk += 4) {
    b16x4 wv = *(const b16x4*)(wrow + kk);
    float w0 = (float)wv[0], w1 = (float)wv[1], w2 = (float)wv[2], w3 = (float)wv[3];
#pragma unroll
    for (int key = 0; key < NKEY; ++key) {
      const float* s = &sh[key][kb + kk];
      acc[key] += w0 * s[0] + w1 * s[1] + w2 * s[2] + w3 * s[3];
    }
  }
#pragma unroll
  for (int key = 0; key < NKEY; ++key) sred[rowIdx][kpart][key] = acc[key];
  __syncthreads();
  if (tid < 64) {
    int key = tid >> 3, j2 = tid & 7;
    float g[4];
#pragma unroll
    for (int gg = 0; gg < 4; ++gg) {
      float s = 0.f;
#pragma unroll
      for (int p = 0; p < 8; ++p) s += sred[gg * 8 + j2][p][key];
      g[gg] = s + bias[gg * HID + j0 + j2];
    }
    size_t ci = (size_t)key * HID + j0 + j2;
    float cv = sigmoidf_(g[1]) * ck[ci] + sigmoidf_(g[0]) * tanhfast_(g[2]);
    ck[ci] = cv;
    hk_out[ci] = sigmoidf_(g[3]) * tanhfast_(cv);
  }
}

__global__ __launch_bounds__(256) void key_mean(
    const float* __restrict__ hk, const float* __restrict__ ck,
    float* __restrict__ h0, float* __restrict__ c0) {
  int j = blockIdx.x * 256 + threadIdx.x;
  float sh_ = 0.f, sc_ = 0.f;
#pragma unroll
  for (int k = 0; k < NKEY; ++k) { sh_ += hk[k * HID + j]; sc_ += ck[k * HID + j]; }
  h0[j] = sh_ * (1.f / NKEY);
  c0[j] = sc_ * (1.f / NKEY);
}

// ---- main pass init ----
__global__ __launch_bounds__(256) void main_init(
    const float* __restrict__ h0, const float* __restrict__ c0,
    const float* __restrict__ x, __hip_bfloat16* __restrict__ A0,
    __hip_bfloat16* __restrict__ A1, float* __restrict__ c) {
  int idx = blockIdx.x * 256 + threadIdx.x;  // 4096*1056
  int b = idx / KTOT, col = idx - b * KTOT;
  if (col < HID) {
    A0[idx] = __float2bfloat16(h0[col]);
    c[b * HID + col] = c0[col];
  } else if (col < HID + DIN) {
    A0[idx] = __float2bfloat16(x[b * (TSTEPS * DIN) + (col - HID)]);
  } else {
    A0[idx] = __float2bfloat16(0.f);
    A1[idx] = __float2bfloat16(0.f);
  }
}

// ---- fused GEMM + LSTM cell: depth-3 counted-vmcnt pipeline ----
// Block: 128 rows x (32 j x 4 gates). Grid dim3(32 jt, 32 mt): flat%8 = jt%8
// -> each XCD holds 4 jt of Wt (~1.1 MB, L2-resident).
__global__ __launch_bounds__(256, 2) void gemm_lstm(
    const __hip_bfloat16* __restrict__ Ain, const __hip_bfloat16* __restrict__ Wt,
    const float* __restrict__ bias, float* __restrict__ cst,
    __hip_bfloat16* __restrict__ Aout, const float* __restrict__ x,
    float* __restrict__ hfin, int t) {
  __shared__ alignas(16) __hip_bfloat16 sA[4][128 * 32];      // 4 x 8KB
  __shared__ alignas(16) __hip_bfloat16 sB[4][4 * 32 * 32];   // 4 x 8KB
  const int tid = threadIdx.x;
  const int lane = tid & 63, wave = tid >> 6;
  const int wr = wave >> 1, wc = wave & 1;
  const int jt = blockIdx.x, mt = blockIdx.y;
  const int brow = mt * 128, j0 = jt * 32;
  const int lrow = lane & 15, kq = lane >> 4;
  const int sx = (lrow >> 1) & 3;

  // staging: LDS dest linear; source k-quad swizzled (measured 0-conflict)
  const int kqs = (tid & 3) ^ ((tid >> 3) & 3);
  const int sArow = tid >> 2;              // 0..63 (+64 for second load)
  const int sBstrip = tid >> 7;            // gate 0/1 (+2 for second load)
  const int sBrow = (tid >> 2) & 31;
  const __hip_bfloat16* gA0 = Ain + (size_t)(brow + sArow) * KTOT + kqs * 8;
  const __hip_bfloat16* gA1 = gA0 + (size_t)64 * KTOT;
  const __hip_bfloat16* gB0 = Wt + (size_t)nprime(sBstrip, j0 + sBrow) * KTOT + kqs * 8;
  const __hip_bfloat16* gB1 = Wt + (size_t)nprime(sBstrip + 2, j0 + sBrow) * KTOT + kqs * 8;

  // fragment-read granule indices (swizzled), constant across K-steps
  int iA[4];
#pragma unroll
  for (int m = 0; m < 4; ++m) {
    int row = wr * 64 + m * 16 + lrow;
    iA[m] = row * 4 + (kq ^ sx);
  }
  // LDS B layout is GATE-MAJOR (staging strips): LDS row = gate*32 + jl,
  // jl = wc*16 + lrow. ((gate*32+jl)>>1)&3 == sx, so same swizzle applies.
  int iB[4];
  {
    int jl = wc * 16 + lrow;
#pragma unroll
    for (int g = 0; g < 4; ++g) iB[g] = (g * 32 + jl) * 4 + (kq ^ sx);
  }

  f32x4 acc[4][4] = {};   // [gate][m]

#define STAGE(buf, kt) do { \
    async16(gA0 + (size_t)(kt) * 32, &sA[buf][tid * 8]); \
    async16(gA1 + (size_t)(kt) * 32, &sA[buf][2048 + tid * 8]); \
    async16(gB0 + (size_t)(kt) * 32, &sB[buf][tid * 8]); \
    async16(gB1 + (size_t)(kt) * 32, &sB[buf][2048 + tid * 8]); \
  } while (0)

  // prologue: stage tiles 0,1,2 (12 vmem instr/wave in flight)
  STAGE(0, 0); STAGE(1, 1); STAGE(2, 2);
  asm volatile("s_waitcnt vmcnt(8)" ::: "memory");   // tile0 landed; 1,2 in flight
  __builtin_amdgcn_s_barrier();

  for (int kt = 0; kt < NTILES; ++kt) {
    if (kt + 3 < NTILES) STAGE((kt + 3) & 3, kt + 3);
    const b16x8* cA = (const b16x8*)sA[kt & 3];
    const b16x8* cB = (const b16x8*)sB[kt & 3];
    b16x8 af[4], bf[4];
#pragma unroll
    for (int m = 0; m < 4; ++m) af[m] = cA[iA[m]];
#pragma unroll
    for (int g = 0; g < 4; ++g) bf[g] = cB[iB[g]];
    __builtin_amdgcn_s_setprio(1);
#pragma unroll
    for (int g = 0; g < 4; ++g)
#pragma unroll
      for (int m = 0; m < 4; ++m)
        acc[g][m] = __builtin_amdgcn_mfma_f32_16x16x32_bf16(af[m], bf[g], acc[g][m], 0, 0, 0);
    __builtin_amdgcn_s_setprio(0);
    // counted wait: next iter needs tile kt+1 fully landed after the barrier
    if (kt + 3 < NTILES)      asm volatile("s_waitcnt vmcnt(8)" ::: "memory");
    else if (kt + 2 < NTILES) asm volatile("s_waitcnt vmcnt(4)" ::: "memory");
    else if (kt + 1 < NTILES) asm volatile("s_waitcnt vmcnt(0)" ::: "memory");
    __builtin_amdgcn_s_barrier();
  }
#undef STAGE

  // ---- fused LSTM cell epilogue ----
  const int j = j0 + wc * 16 + lrow;
  const float b_i = bias[j], b_f = bias[HID + j];
  const float b_g = bias[2 * HID + j], b_o = bias[3 * HID + j];
#pragma unroll
  for (int m = 0; m < 4; ++m) {
    const int row0 = brow + wr * 64 + m * 16 + kq * 4;
#pragma unroll
    for (int r = 0; r < 4; ++r) {
      const int row = row0 + r;
      const size_t ci = (size_t)row * HID + j;
      float gi = acc[0][m][r] + b_i;
      float gf = acc[1][m][r] + b_f;
      float gg = acc[2][m][r] + b_g;
      float go = acc[3][m][r] + b_o;
      float cv = sigmoidf_(gf) * cst[ci] + sigmoidf_(gi) * tanhfast_(gg);
      cst[ci] = cv;
      float h = sigmoidf_(go) * tanhfast_(cv);
      Aout[(size_t)row * KTOT + j] = __float2bfloat16(h);
      if (t == TSTEPS - 1) hfin[ci] = h;
    }
  }
  // inject next x slice (jt==0 blocks own their 128 rows)
  if (jt == 0 && t + 1 < TSTEPS) {
    for (int i = tid; i < 128 * DIN; i += 256) {
      int rr = i / DIN, d = i - rr * DIN;
      Aout[(size_t)(brow + rr) * KTOT + HID + d] =
          __float2bfloat16(x[(size_t)(brow + rr) * (TSTEPS * DIN) + (t + 1) * DIN + d]);
    }
  }
}

// ---- out = hfin @ W_cls + b_cls ----
__global__ __launch_bounds__(256) void classifier(
    const float* __restrict__ hfin, const float* __restrict__ W_cls,
    const float* __restrict__ b_cls, float* __restrict__ out) {
  __shared__ float sw[HID * 10];
  __shared__ float sred[10][257];
  const int b = blockIdx.x, tid = threadIdx.x;
  for (int i = tid; i < HID * 10; i += 256) sw[i] = W_cls[i];
  __syncthreads();
  float acc[10];
#pragma unroll
  for (int cls = 0; cls < 10; ++cls) acc[cls] = 0.f;
  for (int j = tid; j < HID; j += 256) {
    float hv = hfin[(size_t)b * HID + j];
#pragma unroll
    for (int cls = 0; cls < 10; ++cls) acc[cls] += hv * sw[j * 10 + cls];
  }
#pragma unroll
  for (int cls = 0; cls < 10; ++cls) sred[cls][tid] = acc[cls];
  __syncthreads();
  for (int off = 128; off > 0; off >>= 1) {
    if (tid < off)
#pragma unroll
      for (int cls = 0; cls < 10; ++cls) sred[cls][tid] += sred[cls][tid + off];
    __syncthreads();
  }
  if (tid < 10) out[b * 10 + tid] = sred[tid][0] + b_cls[tid];
}

extern "C" void kernel_launch(void* const* d_in, const int* in_sizes, int n_in,
                              void* d_out, int out_size, void* d_ws, size_t ws_size,
                              hipStream_t stream) {
  const float* x      = (const float*)d_in[0];
  const float* keyseq = (const float*)d_in[1];
  const float* W_ih   = (const float*)d_in[2];
  const float* W_hh   = (const float*)d_in[3];
  const float* bias   = (const float*)d_in[4];
  const float* W_cls  = (const float*)d_in[5];
  const float* b_cls  = (const float*)d_in[6];
  float* out = (float*)d_out;
  (void)in_sizes; (void)n_in; (void)out_size; (void)ws_size;

  char* p = (char*)d_ws;
  auto alloc = [&](size_t bytes) { char* r = p; p += (bytes + 255) & ~(size_t)255; return r; };
  __hip_bfloat16* Wt = (__hip_bfloat16*)alloc((size_t)G4H * KTOT * 2);
  __hip_bfloat16* A0 = (__hip_bfloat16*)alloc((size_t)BATCH * KTOT * 2);
  __hip_bfloat16* A1 = (__hip_bfloat16*)alloc((size_t)BATCH * KTOT * 2);
  float* c    = (float*)alloc((size_t)BATCH * HID * 4);
  float* hfin = (float*)alloc((size_t)BATCH * HID * 4);
  float* hk0  = (float*)alloc((size_t)NKEY * HID * 4);   // hk0 then ck contiguous
  float* ck   = (float*)alloc((size_t)NKEY * HID * 4);
  float* hk1  = (float*)alloc((size_t)NKEY * HID * 4);
  float* h0   = (float*)alloc((size_t)HID * 4);
  float* c0   = (float*)alloc((size_t)HID * 4);

  prep_weights<<<dim3(17, 64), 256, 0, stream>>>(W_hh, W_ih, Wt, hk0);

  float* kbuf[2] = {hk0, hk1};
  for (int t = 0; t < TSTEPS; ++t)
    key_step<<<128, 256, 0, stream>>>(Wt, keyseq, bias, kbuf[t & 1], kbuf[(t + 1) & 1], ck, t);
  key_mean<<<4, 256, 0, stream>>>(hk0, ck, h0, c0);

  main_init<<<(BATCH * KTOT) / 256, 256, 0, stream>>>(h0, c0, x, A0, A1, c);

  __hip_bfloat16* Ab[2] = {A0, A1};
  for (int t = 0; t < TSTEPS; ++t)
    gemm_lstm<<<dim3(32, 32), 256, 0, stream>>>(Ab[t & 1], Wt, bias, c,
                                                Ab[(t + 1) & 1], x, hfin, t);
  classifier<<<BATCH, 256, 0, stream>>>(hfin, W_cls, b_cls, out);
}

// Round 7
// 2021.951 us; speedup vs baseline: 3.6970x; 1.3007x over previous
//
#include <hip/hip_runtime.h>
#include <hip/hip_bf16.h>
#include <stdint.h>

#define HID 1024
#define G4H 4096
#define BATCH 4096
#define TSTEPS 28
#define DIN 28
#define KTOT 1056   // 1024 (h) + 28 (x_t) + 4 zero pad = 33 * 32
#define NKEY 8
#define NTILES 33

typedef __attribute__((ext_vector_type(8))) __bf16 b16x8;
typedef __attribute__((ext_vector_type(4))) __bf16 b16x4;
typedef __attribute__((ext_vector_type(4))) float f32x4;
typedef __attribute__((address_space(1))) unsigned int u32_g;
typedef __attribute__((address_space(3))) unsigned int u32_l;

__device__ __forceinline__ void async16(const __hip_bfloat16* g, __hip_bfloat16* l) {
  __builtin_amdgcn_global_load_lds((u32_g*)g, (u32_l*)l, 16, 0, 0);
}

__device__ __forceinline__ float sigmoidf_(float x) { return 1.f / (1.f + __expf(-x)); }
__device__ __forceinline__ float tanhfast_(float x) { return 2.f / (1.f + __expf(-2.f * x)) - 1.f; }

__device__ __forceinline__ int nprime(int gate, int j) {
  return ((j >> 4) << 6) + (gate << 4) + (j & 15);
}

// ---- one-time: Wt[n'][k] bf16 (n' = gate-interleaved) ; zero hk0+ck ----
__global__ __launch_bounds__(256) void prep_weights(
    const float* __restrict__ W_hh, const float* __restrict__ W_ih,
    __hip_bfloat16* __restrict__ Wt, float* __restrict__ kstate) {
  __shared__ float tile[64][65];
  const int k0 = blockIdx.x * 64, n0 = blockIdx.y * 64;
  const int tid = threadIdx.x;
  const int fid = (blockIdx.y * gridDim.x + blockIdx.x) * 256 + tid;
  if (fid < 2 * NKEY * HID) kstate[fid] = 0.f;
  for (int i = tid; i < 4096; i += 256) {
    int kk = i >> 6, nn = i & 63;
    int k = k0 + kk;
    float v = 0.f;
    if (k < HID) v = W_hh[k * G4H + n0 + nn];
    else if (k < HID + DIN) v = W_ih[(k - HID) * G4H + n0 + nn];
    tile[kk][nn] = v;
  }
  __syncthreads();
  for (int i = tid; i < 4096; i += 256) {
    int nn = i >> 6, kk = i & 63;
    int k = k0 + kk;
    int n = n0 + nn;
    int np = nprime(n >> 10, n & 1023);
    if (k < KTOT) Wt[(size_t)np * KTOT + k] = __float2bfloat16(tile[kk][nn]);
  }
}

// ---- key pass: one fused step (bf16 weights, fp32 math) ----
__global__ __launch_bounds__(256) void key_step(
    const __hip_bfloat16* __restrict__ Wt, const float* __restrict__ key_seq,
    const float* __restrict__ bias, const float* __restrict__ hk_in,
    float* __restrict__ hk_out, float* __restrict__ ck, int t) {
  __shared__ float sh[NKEY][KTOT];
  __shared__ float sred[32][8][8];
  const int tid = threadIdx.x;
#pragma unroll
  for (int key = 0; key < NKEY; ++key)
    for (int k = tid; k < HID; k += 256) sh[key][k] = hk_in[key * HID + k];
  for (int i = tid; i < NKEY * 32; i += 256) {
    int key = i >> 5, d = i & 31;
    sh[key][HID + d] = (d < DIN) ? key_seq[key * (TSTEPS * DIN) + t * DIN + d] : 0.f;
  }
  __syncthreads();
  const int rowIdx = tid >> 3;
  const int kpart = tid & 7;
  const int gate = rowIdx >> 3, jj = rowIdx & 7;
  const int j0 = blockIdx.x * 8;
  const int np = nprime(gate, j0 + jj);
  const __hip_bfloat16* wrow = Wt + (size_t)np * KTOT + kpart * 132;
  const int kb = kpart * 132;
  float acc[NKEY];
#pragma unroll
  for (int key = 0; key < NKEY; ++key) acc[key] = 0.f;
  for (int kk = 0; kk < 132; kk += 4) {
    b16x4 wv = *(const b16x4*)(wrow + kk);
    float w0 = (float)wv[0], w1 = (float)wv[1], w2 = (float)wv[2], w3 = (float)wv[3];
#pragma unroll
    for (int key = 0; key < NKEY; ++key) {
      const float* s = &sh[key][kb + kk];
      acc[key] += w0 * s[0] + w1 * s[1] + w2 * s[2] + w3 * s[3];
    }
  }
#pragma unroll
  for (int key = 0; key < NKEY; ++key) sred[rowIdx][kpart][key] = acc[key];
  __syncthreads();
  if (tid < 64) {
    int key = tid >> 3, j2 = tid & 7;
    float g[4];
#pragma unroll
    for (int gg = 0; gg < 4; ++gg) {
      float s = 0.f;
#pragma unroll
      for (int p = 0; p < 8; ++p) s += sred[gg * 8 + j2][p][key];
      g[gg] = s + bias[gg * HID + j0 + j2];
    }
    size_t ci = (size_t)key * HID + j0 + j2;
    float cv = sigmoidf_(g[1]) * ck[ci] + sigmoidf_(g[0]) * tanhfast_(g[2]);
    ck[ci] = cv;
    hk_out[ci] = sigmoidf_(g[3]) * tanhfast_(cv);
  }
}

__global__ __launch_bounds__(256) void key_mean(
    const float* __restrict__ hk, const float* __restrict__ ck,
    float* __restrict__ h0, float* __restrict__ c0) {
  int j = blockIdx.x * 256 + threadIdx.x;
  float sh_ = 0.f, sc_ = 0.f;
#pragma unroll
  for (int k = 0; k < NKEY; ++k) { sh_ += hk[k * HID + j]; sc_ += ck[k * HID + j]; }
  h0[j] = sh_ * (1.f / NKEY);
  c0[j] = sc_ * (1.f / NKEY);
}

// ---- main pass init ----
__global__ __launch_bounds__(256) void main_init(
    const float* __restrict__ h0, const float* __restrict__ c0,
    const float* __restrict__ x, __hip_bfloat16* __restrict__ A0,
    __hip_bfloat16* __restrict__ A1, float* __restrict__ c) {
  int idx = blockIdx.x * 256 + threadIdx.x;  // 4096*1056
  int b = idx / KTOT, col = idx - b * KTOT;
  if (col < HID) {
    A0[idx] = __float2bfloat16(h0[col]);
    c[b * HID + col] = c0[col];
  } else if (col < HID + DIN) {
    A0[idx] = __float2bfloat16(x[b * (TSTEPS * DIN) + (col - HID)]);
  } else {
    A0[idx] = __float2bfloat16(0.f);
    A1[idx] = __float2bfloat16(0.f);
  }
}

// ---- fused GEMM + LSTM cell: 256x128 tile, R2-proven 2-buffer pipeline ----
// Grid dim3(32 jt, 16 mt) = 512 blocks = exactly 2/CU (one co-resident round).
// 512 threads = 8 waves (4M x 2N); per wave 64 rows x (16 j x 4 gates).
__global__ __launch_bounds__(512, 4) void gemm_lstm(
    const __hip_bfloat16* __restrict__ Ain, const __hip_bfloat16* __restrict__ Wt,
    const float* __restrict__ bias, float* __restrict__ cst,
    __hip_bfloat16* __restrict__ Aout, const float* __restrict__ x,
    float* __restrict__ hfin, int t) {
  __shared__ alignas(16) __hip_bfloat16 sA[2][256 * 32];      // 2 x 16KB
  __shared__ alignas(16) __hip_bfloat16 sB[2][4 * 32 * 32];   // 2 x 8KB
  const int tid = threadIdx.x;
  const int lane = tid & 63, wave = tid >> 6;
  const int wr = wave >> 1, wc = wave & 1;    // wr 0..3, wc 0..1
  const int jt = blockIdx.x, mt = blockIdx.y;
  const int brow = mt * 256, j0 = jt * 32;
  const int lrow = lane & 15, kq = lane >> 4;
  const int sx = (lrow >> 1) & 3;

  // staging: LDS dest linear (granules tid, tid+512 for A; tid for B);
  // source k-slot XOR-swizzled (proven 0-conflict pattern)
  const int kqs = (tid & 3) ^ ((tid >> 3) & 3);
  const int sArow = tid >> 2;                 // 0..127 (+128 for second granule)
  const int sBr = tid >> 2;                   // B row 0..127 = gate*32 + jl
  const __hip_bfloat16* gA0 = Ain + (size_t)(brow + sArow) * KTOT + kqs * 8;
  const __hip_bfloat16* gA1 = gA0 + (size_t)128 * KTOT;
  const __hip_bfloat16* gB = Wt + (size_t)nprime(sBr >> 5, j0 + (sBr & 31)) * KTOT + kqs * 8;

  // fragment-read granule indices (16B units), constant across K-steps
  int iA[4];
#pragma unroll
  for (int m = 0; m < 4; ++m) {
    int row = wr * 64 + m * 16 + lrow;
    iA[m] = row * 4 + (kq ^ sx);
  }
  int iB[4];
  {
    int jl = wc * 16 + lrow;
#pragma unroll
    for (int g = 0; g < 4; ++g) iB[g] = (g * 32 + jl) * 4 + (kq ^ sx);
  }

  f32x4 acc[4][4] = {};   // [gate][m]

#define STAGE(buf, kt) do { \
    async16(gA0 + (size_t)(kt) * 32, &sA[buf][tid * 8]); \
    async16(gA1 + (size_t)(kt) * 32, &sA[buf][4096 + tid * 8]); \
    async16(gB + (size_t)(kt) * 32, &sB[buf][tid * 8]); \
  } while (0)

  STAGE(0, 0);
  __syncthreads();

  for (int kt = 0; kt < NTILES; ++kt) {
    if (kt + 1 < NTILES) STAGE((kt + 1) & 1, kt + 1);
    const b16x8* cA = (const b16x8*)sA[kt & 1];
    const b16x8* cB = (const b16x8*)sB[kt & 1];
    b16x8 af[4], bf[4];
#pragma unroll
    for (int m = 0; m < 4; ++m) af[m] = cA[iA[m]];
#pragma unroll
    for (int g = 0; g < 4; ++g) bf[g] = cB[iB[g]];
    __builtin_amdgcn_s_setprio(1);
#pragma unroll
    for (int g = 0; g < 4; ++g)
#pragma unroll
      for (int m = 0; m < 4; ++m)
        acc[g][m] = __builtin_amdgcn_mfma_f32_16x16x32_bf16(af[m], bf[g], acc[g][m], 0, 0, 0);
    __builtin_amdgcn_s_setprio(0);
    __syncthreads();   // drains staged loads (vmcnt) + frag reads (lgkm)
  }
#undef STAGE

  // ---- fused LSTM cell epilogue ----
  const int j = j0 + wc * 16 + lrow;
  const float b_i = bias[j], b_f = bias[HID + j];
  const float b_g = bias[2 * HID + j], b_o = bias[3 * HID + j];
#pragma unroll
  for (int m = 0; m < 4; ++m) {
    const int row0 = brow + wr * 64 + m * 16 + kq * 4;
#pragma unroll
    for (int r = 0; r < 4; ++r) {
      const int row = row0 + r;
      const size_t ci = (size_t)row * HID + j;
      float gi = acc[0][m][r] + b_i;
      float gf = acc[1][m][r] + b_f;
      float gg = acc[2][m][r] + b_g;
      float go = acc[3][m][r] + b_o;
      float cv = sigmoidf_(gf) * cst[ci] + sigmoidf_(gi) * tanhfast_(gg);
      cst[ci] = cv;
      float h = sigmoidf_(go) * tanhfast_(cv);
      Aout[(size_t)row * KTOT + j] = __float2bfloat16(h);
      if (t == TSTEPS - 1) hfin[ci] = h;
    }
  }
  // inject next x slice (jt==0 blocks own their 256 rows)
  if (jt == 0 && t + 1 < TSTEPS) {
    for (int i = tid; i < 256 * DIN; i += 512) {
      int rr = i / DIN, d = i - rr * DIN;
      Aout[(size_t)(brow + rr) * KTOT + HID + d] =
          __float2bfloat16(x[(size_t)(brow + rr) * (TSTEPS * DIN) + (t + 1) * DIN + d]);
    }
  }
}

// ---- out = hfin @ W_cls + b_cls ----
__global__ __launch_bounds__(256) void classifier(
    const float* __restrict__ hfin, const float* __restrict__ W_cls,
    const float* __restrict__ b_cls, float* __restrict__ out) {
  __shared__ float sw[HID * 10];
  __shared__ float sred[10][257];
  const int b = blockIdx.x, tid = threadIdx.x;
  for (int i = tid; i < HID * 10; i += 256) sw[i] = W_cls[i];
  __syncthreads();
  float acc[10];
#pragma unroll
  for (int cls = 0; cls < 10; ++cls) acc[cls] = 0.f;
  for (int j = tid; j < HID; j += 256) {
    float hv = hfin[(size_t)b * HID + j];
#pragma unroll
    for (int cls = 0; cls < 10; ++cls) acc[cls] += hv * sw[j * 10 + cls];
  }
#pragma unroll
  for (int cls = 0; cls < 10; ++cls) sred[cls][tid] = acc[cls];
  __syncthreads();
  for (int off = 128; off > 0; off >>= 1) {
    if (tid < off)
#pragma unroll
      for (int cls = 0; cls < 10; ++cls) sred[cls][tid] += sred[cls][tid + off];
    __syncthreads();
  }
  if (tid < 10) out[b * 10 + tid] = sred[tid][0] + b_cls[tid];
}

extern "C" void kernel_launch(void* const* d_in, const int* in_sizes, int n_in,
                              void* d_out, int out_size, void* d_ws, size_t ws_size,
                              hipStream_t stream) {
  const float* x      = (const float*)d_in[0];
  const float* keyseq = (const float*)d_in[1];
  const float* W_ih   = (const float*)d_in[2];
  const float* W_hh   = (const float*)d_in[3];
  const float* bias   = (const float*)d_in[4];
  const float* W_cls  = (const float*)d_in[5];
  const float* b_cls  = (const float*)d_in[6];
  float* out = (float*)d_out;
  (void)in_sizes; (void)n_in; (void)out_size; (void)ws_size;

  char* p = (char*)d_ws;
  auto alloc = [&](size_t bytes) { char* r = p; p += (bytes + 255) & ~(size_t)255; return r; };
  __hip_bfloat16* Wt = (__hip_bfloat16*)alloc((size_t)G4H * KTOT * 2);
  __hip_bfloat16* A0 = (__hip_bfloat16*)alloc((size_t)BATCH * KTOT * 2);
  __hip_bfloat16* A1 = (__hip_bfloat16*)alloc((size_t)BATCH * KTOT * 2);
  float* c    = (float*)alloc((size_t)BATCH * HID * 4);
  float* hfin = (float*)alloc((size_t)BATCH * HID * 4);
  float* hk0  = (float*)alloc((size_t)NKEY * HID * 4);   // hk0 then ck contiguous
  float* ck   = (float*)alloc((size_t)NKEY * HID * 4);
  float* hk1  = (float*)alloc((size_t)NKEY * HID * 4);
  float* h0   = (float*)alloc((size_t)HID * 4);
  float* c0   = (float*)alloc((size_t)HID * 4);

  prep_weights<<<dim3(17, 64), 256, 0, stream>>>(W_hh, W_ih, Wt, hk0);

  float* kbuf[2] = {hk0, hk1};
  for (int t = 0; t < TSTEPS; ++t)
    key_step<<<128, 256, 0, stream>>>(Wt, keyseq, bias, kbuf[t & 1], kbuf[(t + 1) & 1], ck, t);
  key_mean<<<4, 256, 0, stream>>>(hk0, ck, h0, c0);

  main_init<<<(BATCH * KTOT) / 256, 256, 0, stream>>>(h0, c0, x, A0, A1, c);

  __hip_bfloat16* Ab[2] = {A0, A1};
  for (int t = 0; t < TSTEPS; ++t)
    gemm_lstm<<<dim3(32, 16), 512, 0, stream>>>(Ab[t & 1], Wt, bias, c,
                                                Ab[(t + 1) & 1], x, hfin, t);
  classifier<<<BATCH, 256, 0, stream>>>(hfin, W_cls, b_cls, out);
}